// Round 1
// 630.649 us; speedup vs baseline: 1.0658x; 1.0658x over previous
//
#include <hip/hip_runtime.h>

#define K 11
#define TT 2048
#define NBH 64              // 16-step blocks per half-chain (1024 steps each)
#define START_TAG 10
#define STOP_TAG 9
#define L2E 1.4426950408889634f
#define LN2 0.6931471805599453f

// DPP row-rotate-right by S within 16-lane rows (VALU-latency cross-lane).
template<int S>
__device__ __forceinline__ float ror16(float x) {
    return __int_as_float(__builtin_amdgcn_update_dpp(
        __float_as_int(x), __float_as_int(x), 0x120 + S, 0xF, 0xF, false));
}

// Forward/backward midpoint split: each sequence owned by 32 lanes.
// Lanes 0-15: forward chain a <- E_t .* (W a), rows 0..1023.
// Lanes 16-31: backward chain c <- E_t .* (W^T c), rows 2046..1024 descending,
//   init c = E_2047 .* stop, final dummy step (e=1) applies the closing W^T.
// Both halves share one SIMT instruction stream: per-lane transposed weights,
// per-lane descending base rows, register-order reversal via cndmask.
// Score = ln(sum_s a[s]*r[s]) + (cacc_f + cacc_b)*ln2.
// Doubles occupancy: 2048 waves -> 2 waves/SIMD (was 1).
__global__ __launch_bounds__(256, 2) void crf_nll_kernel(
    const float* __restrict__ feats,
    const int* __restrict__ tags,
    const float* __restrict__ trans,
    float* __restrict__ out,
    int nseq)
{
    __shared__ float Tf[K * 16];   // Tf[next*16+prev] = trans[next][prev]
    __shared__ float Tb[K * 16];   // Tb[g*16+prev]    = trans[prev][g]
    if (threadIdx.x < K * 16) {
        int r = threadIdx.x >> 4, c = threadIdx.x & 15;
        Tf[threadIdx.x] = (c < K) ? trans[r * K + c] : 0.0f;
        Tb[threadIdx.x] = (c < K) ? trans[c * K + r] : 0.0f;
    }
    __syncthreads();

    const int tid = blockIdx.x * blockDim.x + threadIdx.x;
    const int n = threadIdx.x & 15;          // lane within 16-lane row
    const int bwd = (tid >> 4) & 1;          // 0 = forward half, 1 = backward
    const int seq = tid >> 5;
    if (seq >= nseq) return;
    const int st = (n < K) ? n : n - K;      // lanes 11..15 mirror states 0..4

    // Per-lane rotation coefficients. Forward: W[st][p]; backward: W[p][st]
    // (transpose). Same mod-11 gather mapping s(r) in both directions.
    float w[16];
#pragma unroll
    for (int s = 0; s < 16; ++s) w[s] = 0.0f;
#pragma unroll
    for (int r = 0; r < K; ++r) {
        int p = st + r; if (p >= K) p -= K;
        float tw = bwd ? trans[p * K + st] : trans[st * K + p];
        float e = __builtin_amdgcn_exp2f(tw * L2E);
        int s = (r == 0) ? 0 : ((n + r <= 15) ? r : r + 5);
        w[s] = e;
    }

    const float* fb = feats + (size_t)seq * TT * K;
    const int* tb = tags + (size_t)seq * TT;
    const float* Tg = bwd ? Tb : Tf;

    // Row 2047 (consumed only by the backward init).
    const float fl = fb[(size_t)(TT - 1) * K + st];
    const int gl = tb[TT - 1];

    float a;
    int prev;
    float goldt, goldf;
    if (bwd) {
        // c_2047 = E_2047 .* stop ; gold: STOP pair + row-2047 emission
        a = __builtin_amdgcn_exp2f((trans[STOP_TAG * K + st] + fl) * L2E);
        prev = gl;
        goldt = Tf[STOP_TAG * 16 + gl];
        goldf = (n == gl) ? fl : 0.0f;
    } else {
        a = (n == START_TAG) ? 1.0f : 0.0f;
        prev = START_TAG;
        goldt = 0.0f;
        goldf = 0.0f;
    }
    int cacc = 0;

    float fA[16], fB[16];
    int gA[16], gB[16];

    auto prefetch = [&](float (&f)[16], int (&g)[16], int blk) {
        // fwd block b: rows 16b..16b+15 ascending.
        // bwd block b: rows 2046-16b..2031-16b descending = ascending window
        //   [2031-16b, 2046-16b], register-reversed.
        const int base_row = bwd ? (2031 - (blk << 4)) : (blk << 4);
        const float* fp = fb + (size_t)base_row * K + st;
        const int* tp = tb + base_row;
        float tf[16]; int tg[16];
#pragma unroll
        for (int j = 0; j < 16; ++j) tf[j] = fp[j * K];
#pragma unroll
        for (int j = 0; j < 16; ++j) tg[j] = tp[j];
#pragma unroll
        for (int j = 0; j < 16; ++j) {
            f[j] = bwd ? tf[15 - j] : tf[j];
            g[j] = bwd ? tg[15 - j] : tg[j];
        }
        // Backward's last slot (global step 1023, row 1023) is the dummy
        // step: e=1 performs the closing r = W^T c. Its tag g_1023 is kept —
        // it supplies the boundary gold pair trans[g_1024][g_1023].
        if (blk == NBH - 1 && bwd) f[15] = 0.0f;
    };

    auto process = [&](float (&f)[16], int (&g)[16]) {
        // phase 0: issue all gold-transition LDS reads (addresses off-chain)
        float tv[16];
        {
            int pv = prev;
#pragma unroll
            for (int j = 0; j < 16; ++j) {
                tv[j] = Tg[(g[j] << 4) + pv];
                pv = g[j];
            }
        }
        // phase 1: hoisted transcendentals (hide LDS latency)
        float e[16];
#pragma unroll
        for (int j = 0; j < 16; ++j)
            e[j] = __builtin_amdgcn_exp2f(f[j] * L2E);
        // phase 2: pure-VALU serial chain (identical for both directions)
#pragma unroll
        for (int j = 0; j < 16; ++j) {
            float av = a;
            float acc0 = w[0] * av;
            float acc1 = w[1] * ror16<1>(av);
            float acc2 = w[2] * ror16<2>(av);
            float acc3 = w[3] * ror16<3>(av);
            acc0 = fmaf(w[4],  ror16<4>(av),  acc0);
            acc1 = fmaf(w[5],  ror16<5>(av),  acc1);
            acc2 = fmaf(w[6],  ror16<6>(av),  acc2);
            acc3 = fmaf(w[7],  ror16<7>(av),  acc3);
            acc0 = fmaf(w[8],  ror16<8>(av),  acc0);
            acc1 = fmaf(w[9],  ror16<9>(av),  acc1);
            acc2 = fmaf(w[10], ror16<10>(av), acc2);
            acc3 = fmaf(w[11], ror16<11>(av), acc3);
            acc0 = fmaf(w[12], ror16<12>(av), acc0);
            acc1 = fmaf(w[13], ror16<13>(av), acc1);
            acc2 = fmaf(w[14], ror16<14>(av), acc2);
            acc3 = fmaf(w[15], ror16<15>(av), acc3);
            float S = (acc0 + acc1) + (acc2 + acc3);
            a = S * e[j];
            if ((j & 7) == 7) {  // exact pow2 renorm
                float m = a;
                m = fmaxf(m, ror16<1>(m));
                m = fmaxf(m, ror16<2>(m));
                m = fmaxf(m, ror16<4>(m));
                m = fmaxf(m, ror16<8>(m));
                int ex = ((__float_as_int(m) >> 23) & 0xFF) - 127;
                a *= __int_as_float((127 - ex) << 23);   // exact *2^-ex
                cacc += ex;
            }
        }
        // phase 3: gold sums
        float gt = 0.0f, gf = 0.0f;
#pragma unroll
        for (int j = 0; j < 16; ++j) {
            gt += tv[j];
            gf += (n == g[j]) ? f[j] : 0.0f;
        }
        goldt += gt;
        goldf += gf;
        prev = g[15];
    };

    prefetch(fA, gA, 0);
#pragma unroll 1
    for (int b = 0; b < NBH; b += 2) {
        int b1 = (b + 1 < NBH) ? b + 1 : NBH - 1;
        prefetch(fB, gB, b1);
        process(fA, gA);
        int b2 = (b + 2 < NBH) ? b + 2 : NBH - 1;
        prefetch(fA, gA, b2);   // tail re-read, unused
        process(fB, gB);
    }

    // Combine: fwd rows hold a_M, bwd rows hold r. Score needs
    // sum_{s<K} a[s]*r[s]; zero mirror lanes on both sides, pair via xor-16.
    float v = (n < K) ? a : 0.0f;
    float pv2 = __shfl_xor(v, 16);
    float prod = v * pv2;
    prod += ror16<1>(prod);
    prod += ror16<2>(prod);
    prod += ror16<4>(prod);
    prod += ror16<8>(prod);
    int ctot = cacc + __shfl_xor(cacc, 16);
    float fs = (__builtin_amdgcn_logf(prod) + (float)ctot) * LN2;

    goldf += ror16<1>(goldf);
    goldf += ror16<2>(goldf);
    goldf += ror16<4>(goldf);
    goldf += ror16<8>(goldf);
    float G = goldt + goldf;        // uniform within each 16-lane row
    G += __shfl_xor(G, 16);         // fwd half + bwd half

    if ((threadIdx.x & 31) == 0) out[seq] = fs - G;
}

extern "C" void kernel_launch(void* const* d_in, const int* in_sizes, int n_in,
                              void* d_out, int out_size, void* d_ws, size_t ws_size,
                              hipStream_t stream) {
    const float* feats = (const float*)d_in[0];
    const int* tags = (const int*)d_in[1];
    const float* trans = (const float*)d_in[2];
    float* out = (float*)d_out;
    const int nseq = in_sizes[1] / TT;                         // 4096
    const int threads = 256;
    const int blocks = (nseq * 32 + threads - 1) / threads;    // 512
    hipLaunchKernelGGL(crf_nll_kernel, dim3(blocks), dim3(threads), 0, stream,
                       feats, tags, trans, out, nseq);
}